// Round 2
// baseline (589.791 us; speedup 1.0000x reference)
//
#include <hip/hip_runtime.h>
#include <hip/hip_bf16.h>

typedef __bf16 bf16;
typedef __bf16 bf16x4 __attribute__((ext_vector_type(4)));
typedef __bf16 bf16x8 __attribute__((ext_vector_type(8)));
typedef float  f32x2  __attribute__((ext_vector_type(2)));
typedef float  f32x4  __attribute__((ext_vector_type(4)));

static constexpr int NB  = 16;
static constexpr int NN  = 2048;
static constexpr int HID = 128;

// async 16B global -> LDS. LDS dest is wave-uniform base + lane*16.
__device__ __forceinline__ void gload_lds16(const bf16* g, bf16* l) {
    __builtin_amdgcn_global_load_lds(
        (const __attribute__((address_space(1))) unsigned int*)g,
        (__attribute__((address_space(3))) unsigned int*)l, 16, 0, 0);
}

// ---------------------------------------------------------------------------
// adj fp32 -> bf16 (one clean memory-bound pass; 268MB read + 134MB write)
// ---------------------------------------------------------------------------
__global__ __launch_bounds__(256) void convert_adj(const float* __restrict__ A,
                                                   bf16* __restrict__ B, long n8) {
    long i = (long)blockIdx.x * blockDim.x + threadIdx.x;
    long stride = (long)gridDim.x * blockDim.x;
    for (; i < n8; i += stride) {
        f32x4 a = *(const f32x4*)(A + i * 8);
        f32x4 b = *(const f32x4*)(A + i * 8 + 4);
        bf16x8 o = {(bf16)a.x, (bf16)a.y, (bf16)a.z, (bf16)a.w,
                    (bf16)b.x, (bf16)b.y, (bf16)b.z, (bf16)b.w};
        *(bf16x8*)(B + i * 8) = o;
    }
}

// ---------------------------------------------------------------------------
// prep: W (128x128 fp32, [k][n]) -> WT bf16 [n][k], for all 3 layers
// ---------------------------------------------------------------------------
__global__ __launch_bounds__(256) void prep_wt(const float* __restrict__ W0,
                                               const float* __restrict__ W1,
                                               const float* __restrict__ W2,
                                               bf16* __restrict__ WT) {
    int l = blockIdx.x;
    const float* W = (l == 0) ? W0 : (l == 1) ? W1 : W2;
    bf16* out = WT + l * 128 * 128;
    int tid = threadIdx.x;
#pragma unroll
    for (int i = 0; i < 64; ++i) {
        int idx = i * 256 + tid;
        int k = idx >> 7, n = idx & 127;
        out[n * 128 + k] = (bf16)W[idx];
    }
}

// ---------------------------------------------------------------------------
// small GEMM: tmp = h @ W, output TRANSPOSED as tmpT[b][n][m] (bf16)
// ---------------------------------------------------------------------------
template<typename TA>
__global__ __launch_bounds__(256) void small_gemm(const TA* __restrict__ A,
                                                  const bf16* __restrict__ WT,
                                                  bf16* __restrict__ tmpT) {
    __shared__ bf16 smem[2 * 128 * 72];
    bf16* As = smem;
    bf16* Bs = smem + 128 * 72;

    const int tid  = threadIdx.x;
    const int wave = tid >> 6, lane = tid & 63;
    const int c0 = lane & 15, q = lane >> 4;
    const int blk = blockIdx.x;
    const int row_g0 = blk * 128;

    f32x4 acc[2][8] = {};

    for (int kk = 0; kk < 2; ++kk) {
        const int k0 = kk * 64;
        if constexpr (sizeof(TA) == 4) {
#pragma unroll
            for (int i = 0; i < 8; ++i) {
                int flat = i * 1024 + tid * 4;
                int row = flat >> 6, col = flat & 63;
                f32x4 v = *(const f32x4*)(A + (size_t)(row_g0 + row) * 128 + k0 + col);
                bf16x4 o = { (bf16)v.x, (bf16)v.y, (bf16)v.z, (bf16)v.w };
                *(bf16x4*)(As + row * 72 + col) = o;
            }
        } else {
#pragma unroll
            for (int i = 0; i < 4; ++i) {
                int flat = i * 2048 + tid * 8;
                int row = flat >> 6, col = flat & 63;
                bf16x8 v = *(const bf16x8*)((const bf16*)A + (size_t)(row_g0 + row) * 128 + k0 + col);
                *(bf16x8*)(As + row * 72 + col) = v;
            }
        }
#pragma unroll
        for (int i = 0; i < 4; ++i) {
            int flat = i * 2048 + tid * 8;
            int row = flat >> 6, col = flat & 63;
            bf16x8 v = *(const bf16x8*)(WT + (size_t)row * 128 + k0 + col);
            *(bf16x8*)(Bs + row * 72 + col) = v;
        }
        __syncthreads();
#pragma unroll
        for (int ks = 0; ks < 2; ++ks) {
            bf16x8 af[2];
#pragma unroll
            for (int mt = 0; mt < 2; ++mt)
                af[mt] = *(const bf16x8*)(As + (wave * 32 + mt * 16 + c0) * 72 + ks * 32 + q * 8);
#pragma unroll
            for (int nt = 0; nt < 8; ++nt) {
                bf16x8 bfr = *(const bf16x8*)(Bs + (nt * 16 + c0) * 72 + ks * 32 + q * 8);
#pragma unroll
                for (int mt = 0; mt < 2; ++mt)
                    acc[mt][nt] = __builtin_amdgcn_mfma_f32_16x16x32_bf16(af[mt], bfr, acc[mt][nt], 0, 0, 0);
            }
        }
        __syncthreads();
    }

    // transposed write-out through LDS: Cs[n][m], row stride 136
    bf16* Cs = smem;
#pragma unroll
    for (int mt = 0; mt < 2; ++mt) {
        int mbase = wave * 32 + mt * 16 + q * 4;
#pragma unroll
        for (int nt = 0; nt < 8; ++nt) {
            int n = nt * 16 + c0;
#pragma unroll
            for (int r = 0; r < 4; ++r)
                Cs[n * 136 + mbase + r] = (bf16)acc[mt][nt][r];
        }
    }
    __syncthreads();
    const int b    = blk >> 4;
    const int row0 = (blk & 15) * 128;
    bf16* outp = tmpT + (size_t)b * 128 * 2048;
#pragma unroll
    for (int i = 0; i < 8; ++i) {
        int flat = i * 2048 + tid * 8;
        int n = flat >> 7, m = flat & 127;
        bf16x8 v = *(const bf16x8*)(Cs + n * 136 + m);
        *(bf16x8*)(outp + (size_t)n * 2048 + row0 + m) = v;
    }
}

// ---------------------------------------------------------------------------
// big GEMM, K-split=2: part[ksp] = adj[b][:, ksp*1024 : +1024] @ tmp-half
// BM=128, BN=128(full), BK=64, 16 iters. 256 thr = 4 waves, wave-tile 64x64.
// global_load_lds staging with XOR-swizzled source addressing (no LDS pad).
// ---------------------------------------------------------------------------
__global__ __launch_bounds__(256, 2) void big_gemm(const bf16* __restrict__ adjB,
                                                   const bf16* __restrict__ Bt,
                                                   float* __restrict__ part) {
    __shared__ bf16 As[128 * 64];   // 16KB, chunk(16B) p = row*8 + (colblk ^ (row&7))
    __shared__ bf16 Bs[128 * 64];   // 16KB, same layout over [n][k]

    const int tid  = threadIdx.x;
    const int wave = tid >> 6, lane = tid & 63;
    const int c0 = lane & 15, q = lane >> 4;
    const int m0  = blockIdx.x * 128;
    const int ksp = blockIdx.y;
    const int b   = blockIdx.z;
    const size_t abase = (size_t)b * NN * NN;
    const bf16* Btb = Bt + (size_t)b * HID * NN;
    const int mrow = (wave >> 1) * 64, ncol = (wave & 1) * 64;

    f32x4 acc[4][4] = {};

    // staging descriptors: physical chunk p = j*256 + wave*64 + lane
    int prow[4], pcb[4];
#pragma unroll
    for (int j = 0; j < 4; ++j) {
        int p = j * 256 + wave * 64 + lane;
        prow[j] = p >> 3;
        pcb[j]  = (p & 7) ^ (prow[j] & 7);
    }
    const int ldsbase = wave * 64 * 8;   // elements; per-issue +256*8

    for (int kk = 0; kk < 16; ++kk) {
        const int k0 = ksp * 1024 + kk * 64;
#pragma unroll
        for (int j = 0; j < 4; ++j) {
            gload_lds16(adjB + abase + (size_t)(m0 + prow[j]) * NN + k0 + pcb[j] * 8,
                        As + j * 2048 + ldsbase);
            gload_lds16(Btb + (size_t)prow[j] * NN + k0 + pcb[j] * 8,
                        Bs + j * 2048 + ldsbase);
        }
        __syncthreads();
#pragma unroll
        for (int ks = 0; ks < 2; ++ks) {
            bf16x8 af[4], bfr[4];
#pragma unroll
            for (int mt = 0; mt < 4; ++mt) {
                int row = mrow + mt * 16 + c0;
                int cb  = (ks * 4 + q) ^ (row & 7);
                af[mt] = *(const bf16x8*)(As + row * 64 + cb * 8);
            }
#pragma unroll
            for (int nt = 0; nt < 4; ++nt) {
                int row = ncol + nt * 16 + c0;
                int cb  = (ks * 4 + q) ^ (row & 7);
                bfr[nt] = *(const bf16x8*)(Bs + row * 64 + cb * 8);
            }
#pragma unroll
            for (int mt = 0; mt < 4; ++mt)
#pragma unroll
                for (int nt = 0; nt < 4; ++nt)
                    acc[mt][nt] = __builtin_amdgcn_mfma_f32_16x16x32_bf16(af[mt], bfr[nt], acc[mt][nt], 0, 0, 0);
        }
        __syncthreads();
    }

    float* pb = part + ((size_t)(ksp * NB + b) * NN + m0) * HID;
#pragma unroll
    for (int mt = 0; mt < 4; ++mt)
#pragma unroll
        for (int r = 0; r < 4; ++r) {
            int m = mrow + mt * 16 + q * 4 + r;
#pragma unroll
            for (int nt = 0; nt < 4; ++nt) {
                int n = ncol + nt * 16 + c0;
                pb[(size_t)m * HID + n] = acc[mt][nt][r];
            }
        }
}

// ---------------------------------------------------------------------------
// reduce 2 K-split partials + bias + LayerNorm + ReLU.  One wave per row.
// ---------------------------------------------------------------------------
template<bool OUTF32>
__global__ __launch_bounds__(256) void reduce_ln(const float* __restrict__ part,
                                                 const float* __restrict__ bias,
                                                 const float* __restrict__ gamma,
                                                 const float* __restrict__ betap,
                                                 bf16* __restrict__ outB,
                                                 float* __restrict__ outF) {
    const int tid = threadIdx.x, wave = tid >> 6, lane = tid & 63;
    const size_t row = (size_t)blockIdx.x * 4 + wave;        // 0..32767
    const size_t off = row * HID + lane * 2;
    f32x2 p0 = *(const f32x2*)(part + off);
    f32x2 p1 = *(const f32x2*)(part + (size_t)NB * NN * HID + off);
    f32x2 bv = *(const f32x2*)(bias + lane * 2);
    float x0 = p0.x + p1.x + bv.x;
    float x1 = p0.y + p1.y + bv.y;
    float s1 = x0 + x1, s2 = x0 * x0 + x1 * x1;
#pragma unroll
    for (int o = 1; o < 64; o <<= 1) { s1 += __shfl_xor(s1, o); s2 += __shfl_xor(s2, o); }
    float mu  = s1 * (1.f / 128.f);
    float var = s2 * (1.f / 128.f) - mu * mu;
    float rs  = rsqrtf(var + 1e-5f);
    f32x2 gv = *(const f32x2*)(gamma + lane * 2);
    f32x2 be = *(const f32x2*)(betap + lane * 2);
    float o0 = fmaxf((x0 - mu) * rs * gv.x + be.x, 0.f);
    float o1 = fmaxf((x1 - mu) * rs * gv.y + be.y, 0.f);
    if constexpr (OUTF32) {
        f32x2 o = {o0, o1};
        *(f32x2*)(outF + off) = o;
    } else {
        bf16* p = outB + off;
        p[0] = (bf16)o0; p[1] = (bf16)o1;
    }
}

// ---------------------------------------------------------------------------
extern "C" void kernel_launch(void* const* d_in, const int* in_sizes, int n_in,
                              void* d_out, int out_size, void* d_ws, size_t ws_size,
                              hipStream_t stream) {
    const float* x   = (const float*)d_in[0];
    const float* adj = (const float*)d_in[1];
    const float* W[3]  = {(const float*)d_in[2],  (const float*)d_in[6],  (const float*)d_in[10]};
    const float* bb[3] = {(const float*)d_in[3],  (const float*)d_in[7],  (const float*)d_in[11]};
    const float* gg[3] = {(const float*)d_in[4],  (const float*)d_in[8],  (const float*)d_in[12]};
    const float* be[3] = {(const float*)d_in[5],  (const float*)d_in[9],  (const float*)d_in[13]};

    char* ws = (char*)d_ws;
    size_t off = 0;
    auto alloc = [&](size_t bytes) { char* p = ws + off; off = (off + bytes + 255) & ~(size_t)255; return p; };
    bf16*  WT   = (bf16*) alloc((size_t)3 * 128 * 128 * 2);
    bf16*  tmpT = (bf16*) alloc((size_t)NB * HID * NN * 2);      // 8 MiB
    bf16*  hB   = (bf16*) alloc((size_t)NB * NN * HID * 2);      // 8 MiB
    bf16*  adjB = (bf16*) alloc((size_t)NB * NN * NN * 2);       // 128 MiB
    float* part = (float*)alloc((size_t)2 * NB * NN * HID * 4);  // 32 MiB

    float* outF = (float*)d_out;

    prep_wt<<<3, 256, 0, stream>>>(W[0], W[1], W[2], WT);
    convert_adj<<<8192, 256, 0, stream>>>(adj, adjB, (long)NB * NN * NN / 8);

    dim3 bg(16, 2, 16);
    // ---- layer 0 ----
    small_gemm<float><<<256, 256, 0, stream>>>(x, WT, tmpT);
    big_gemm<<<bg, 256, 0, stream>>>(adjB, tmpT, part);
    reduce_ln<false><<<8192, 256, 0, stream>>>(part, bb[0], gg[0], be[0], hB, nullptr);
    // ---- layer 1 ----
    small_gemm<bf16><<<256, 256, 0, stream>>>(hB, WT + 128 * 128, tmpT);
    big_gemm<<<bg, 256, 0, stream>>>(adjB, tmpT, part);
    reduce_ln<false><<<8192, 256, 0, stream>>>(part, bb[1], gg[1], be[1], hB, nullptr);
    // ---- layer 2 ----
    small_gemm<bf16><<<256, 256, 0, stream>>>(hB, WT + 2 * 128 * 128, tmpT);
    big_gemm<<<bg, 256, 0, stream>>>(adjB, tmpT, part);
    reduce_ln<true><<<8192, 256, 0, stream>>>(part, bb[2], gg[2], be[2], nullptr, outF);
}

// Round 3
// 583.875 us; speedup vs baseline: 1.0101x; 1.0101x over previous
//
#include <hip/hip_runtime.h>
#include <hip/hip_bf16.h>

typedef __bf16 bf16;
typedef __bf16 bf16x4 __attribute__((ext_vector_type(4)));
typedef __bf16 bf16x8 __attribute__((ext_vector_type(8)));
typedef float  f32x2  __attribute__((ext_vector_type(2)));
typedef float  f32x4  __attribute__((ext_vector_type(4)));

static constexpr int NB  = 16;
static constexpr int NN  = 2048;
static constexpr int HID = 128;

// async 16B global -> LDS. LDS dest is wave-uniform base + lane*16.
__device__ __forceinline__ void gload_lds16(const bf16* g, bf16* l) {
    __builtin_amdgcn_global_load_lds(
        (const __attribute__((address_space(1))) unsigned int*)g,
        (__attribute__((address_space(3))) unsigned int*)l, 16, 0, 0);
}

// ---------------------------------------------------------------------------
// prep: W (128x128 fp32, [k][n]) -> WT bf16 [n][k], for all 3 layers
// ---------------------------------------------------------------------------
__global__ __launch_bounds__(256) void prep_wt(const float* __restrict__ W0,
                                               const float* __restrict__ W1,
                                               const float* __restrict__ W2,
                                               bf16* __restrict__ WT) {
    int l = blockIdx.x;
    const float* W = (l == 0) ? W0 : (l == 1) ? W1 : W2;
    bf16* out = WT + l * 128 * 128;
    int tid = threadIdx.x;
#pragma unroll
    for (int i = 0; i < 64; ++i) {
        int idx = i * 256 + tid;
        int k = idx >> 7, n = idx & 127;
        out[n * 128 + k] = (bf16)W[idx];
    }
}

// ---------------------------------------------------------------------------
// small GEMM: tmp = h @ W, output TRANSPOSED as tmpT[b][n][m] (bf16)
// ---------------------------------------------------------------------------
template<typename TA>
__global__ __launch_bounds__(256) void small_gemm(const TA* __restrict__ A,
                                                  const bf16* __restrict__ WT,
                                                  bf16* __restrict__ tmpT) {
    __shared__ bf16 smem[2 * 128 * 72];
    bf16* As = smem;
    bf16* Bs = smem + 128 * 72;

    const int tid  = threadIdx.x;
    const int wave = tid >> 6, lane = tid & 63;
    const int c0 = lane & 15, q = lane >> 4;
    const int blk = blockIdx.x;
    const int row_g0 = blk * 128;

    f32x4 acc[2][8] = {};

    for (int kk = 0; kk < 2; ++kk) {
        const int k0 = kk * 64;
        if constexpr (sizeof(TA) == 4) {
#pragma unroll
            for (int i = 0; i < 8; ++i) {
                int flat = i * 1024 + tid * 4;
                int row = flat >> 6, col = flat & 63;
                f32x4 v = *(const f32x4*)(A + (size_t)(row_g0 + row) * 128 + k0 + col);
                bf16x4 o = { (bf16)v.x, (bf16)v.y, (bf16)v.z, (bf16)v.w };
                *(bf16x4*)(As + row * 72 + col) = o;
            }
        } else {
#pragma unroll
            for (int i = 0; i < 4; ++i) {
                int flat = i * 2048 + tid * 8;
                int row = flat >> 6, col = flat & 63;
                bf16x8 v = *(const bf16x8*)((const bf16*)A + (size_t)(row_g0 + row) * 128 + k0 + col);
                *(bf16x8*)(As + row * 72 + col) = v;
            }
        }
#pragma unroll
        for (int i = 0; i < 4; ++i) {
            int flat = i * 2048 + tid * 8;
            int row = flat >> 6, col = flat & 63;
            bf16x8 v = *(const bf16x8*)(WT + (size_t)row * 128 + k0 + col);
            *(bf16x8*)(Bs + row * 72 + col) = v;
        }
        __syncthreads();
#pragma unroll
        for (int ks = 0; ks < 2; ++ks) {
            bf16x8 af[2];
#pragma unroll
            for (int mt = 0; mt < 2; ++mt)
                af[mt] = *(const bf16x8*)(As + (wave * 32 + mt * 16 + c0) * 72 + ks * 32 + q * 8);
#pragma unroll
            for (int nt = 0; nt < 8; ++nt) {
                bf16x8 bfr = *(const bf16x8*)(Bs + (nt * 16 + c0) * 72 + ks * 32 + q * 8);
#pragma unroll
                for (int mt = 0; mt < 2; ++mt)
                    acc[mt][nt] = __builtin_amdgcn_mfma_f32_16x16x32_bf16(af[mt], bfr, acc[mt][nt], 0, 0, 0);
            }
        }
        __syncthreads();
    }

    // transposed write-out through LDS: Cs[n][m], row stride 136
    bf16* Cs = smem;
#pragma unroll
    for (int mt = 0; mt < 2; ++mt) {
        int mbase = wave * 32 + mt * 16 + q * 4;
#pragma unroll
        for (int nt = 0; nt < 8; ++nt) {
            int n = nt * 16 + c0;
#pragma unroll
            for (int r = 0; r < 4; ++r)
                Cs[n * 136 + mbase + r] = (bf16)acc[mt][nt][r];
        }
    }
    __syncthreads();
    const int b    = blk >> 4;
    const int row0 = (blk & 15) * 128;
    bf16* outp = tmpT + (size_t)b * 128 * 2048;
#pragma unroll
    for (int i = 0; i < 8; ++i) {
        int flat = i * 2048 + tid * 8;
        int n = flat >> 7, m = flat & 127;
        bf16x8 v = *(const bf16x8*)(Cs + n * 136 + m);
        *(bf16x8*)(outp + (size_t)n * 2048 + row0 + m) = v;
    }
}

// ---------------------------------------------------------------------------
// big GEMM, K-split=2: part[ksp] = adj[b][:, ksp*1024 : +1024] @ tmp-half
// BM=128, BN=128(full), BK=64, 16 iters. 256 thr = 4 waves, wave-tile 64x64.
// LDS layout (both tiles): physical 16B chunk p = row*8 + (colblk ^ (row&7)).
// AMODE 1: A staged from fp32 adj (in-register cvt) + side-write of adjB bf16.
// AMODE 2: A staged from adjB via async global_load_lds (swizzle on src addr).
// ---------------------------------------------------------------------------
template<int AMODE>
__global__ __launch_bounds__(256, 2) void big_gemm(const float* __restrict__ Af,
                                                   bf16* __restrict__ adjB,
                                                   const bf16* __restrict__ Bt,
                                                   float* __restrict__ part) {
    __shared__ bf16 As[128 * 64];   // 16KB
    __shared__ bf16 Bs[128 * 64];   // 16KB

    const int tid  = threadIdx.x;
    const int wave = tid >> 6, lane = tid & 63;
    const int c0 = lane & 15, q = lane >> 4;
    const int m0  = blockIdx.x * 128;
    const int ksp = blockIdx.y;
    const int b   = blockIdx.z;
    const size_t abase = (size_t)b * NN * NN;
    const bf16* Btb = Bt + (size_t)b * HID * NN;
    const int mrow = (wave >> 1) * 64, ncol = (wave & 1) * 64;

    f32x4 acc[4][4] = {};

    // async staging descriptors: physical chunk p = j*256 + wave*64 + lane
    int prow[4], pcb[4];
#pragma unroll
    for (int j = 0; j < 4; ++j) {
        int p = j * 256 + wave * 64 + lane;
        prow[j] = p >> 3;
        pcb[j]  = (p & 7) ^ (prow[j] & 7);
    }
    const int ldsbase = wave * 64 * 8;

    for (int kk = 0; kk < 16; ++kk) {
        const int k0 = ksp * 1024 + kk * 64;
        if constexpr (AMODE == 1) {
            // manual fp32 -> bf16 staging (swizzled) + adjB side-write
#pragma unroll
            for (int j = 0; j < 4; ++j) {
                int g = j * 256 + tid;          // global 16B-bf16 chunk id
                int grow = g >> 3, gcb = g & 7;
                const float* src = Af + abase + (size_t)(m0 + grow) * NN + k0 + gcb * 8;
                f32x4 a  = *(const f32x4*)src;
                f32x4 b2 = *(const f32x4*)(src + 4);
                bf16x8 o = {(bf16)a.x, (bf16)a.y, (bf16)a.z, (bf16)a.w,
                            (bf16)b2.x, (bf16)b2.y, (bf16)b2.z, (bf16)b2.w};
                *(bf16x8*)(As + (grow * 8 + (gcb ^ (grow & 7))) * 8) = o;
                *(bf16x8*)(adjB + abase + (size_t)(m0 + grow) * NN + k0 + gcb * 8) = o;
            }
        } else {
#pragma unroll
            for (int j = 0; j < 4; ++j)
                gload_lds16(adjB + abase + (size_t)(m0 + prow[j]) * NN + k0 + pcb[j] * 8,
                            As + j * 2048 + ldsbase);
        }
#pragma unroll
        for (int j = 0; j < 4; ++j)
            gload_lds16(Btb + (size_t)prow[j] * NN + k0 + pcb[j] * 8,
                        Bs + j * 2048 + ldsbase);
        __syncthreads();
#pragma unroll
        for (int ks = 0; ks < 2; ++ks) {
            bf16x8 af[4], bfr[4];
#pragma unroll
            for (int mt = 0; mt < 4; ++mt) {
                int row = mrow + mt * 16 + c0;
                int cb  = (ks * 4 + q) ^ (row & 7);
                af[mt] = *(const bf16x8*)(As + row * 64 + cb * 8);
            }
#pragma unroll
            for (int nt = 0; nt < 4; ++nt) {
                int row = ncol + nt * 16 + c0;
                int cb  = (ks * 4 + q) ^ (row & 7);
                bfr[nt] = *(const bf16x8*)(Bs + row * 64 + cb * 8);
            }
#pragma unroll
            for (int mt = 0; mt < 4; ++mt)
#pragma unroll
                for (int nt = 0; nt < 4; ++nt)
                    acc[mt][nt] = __builtin_amdgcn_mfma_f32_16x16x32_bf16(af[mt], bfr[nt], acc[mt][nt], 0, 0, 0);
        }
        __syncthreads();
    }

    float* pb = part + ((size_t)(ksp * NB + b) * NN + m0) * HID;
#pragma unroll
    for (int mt = 0; mt < 4; ++mt)
#pragma unroll
        for (int r = 0; r < 4; ++r) {
            int m = mrow + mt * 16 + q * 4 + r;
#pragma unroll
            for (int nt = 0; nt < 4; ++nt) {
                int n = ncol + nt * 16 + c0;
                pb[(size_t)m * HID + n] = acc[mt][nt][r];
            }
        }
}

// ---------------------------------------------------------------------------
// reduce 2 K-split partials + bias + LayerNorm + ReLU.  One wave per row.
// ---------------------------------------------------------------------------
template<bool OUTF32>
__global__ __launch_bounds__(256) void reduce_ln(const float* __restrict__ part,
                                                 const float* __restrict__ bias,
                                                 const float* __restrict__ gamma,
                                                 const float* __restrict__ betap,
                                                 bf16* __restrict__ outB,
                                                 float* __restrict__ outF) {
    const int tid = threadIdx.x, wave = tid >> 6, lane = tid & 63;
    const size_t row = (size_t)blockIdx.x * 4 + wave;
    const size_t off = row * HID + lane * 2;
    f32x2 p0 = *(const f32x2*)(part + off);
    f32x2 p1 = *(const f32x2*)(part + (size_t)NB * NN * HID + off);
    f32x2 bv = *(const f32x2*)(bias + lane * 2);
    float x0 = p0.x + p1.x + bv.x;
    float x1 = p0.y + p1.y + bv.y;
    float s1 = x0 + x1, s2 = x0 * x0 + x1 * x1;
#pragma unroll
    for (int o = 1; o < 64; o <<= 1) { s1 += __shfl_xor(s1, o); s2 += __shfl_xor(s2, o); }
    float mu  = s1 * (1.f / 128.f);
    float var = s2 * (1.f / 128.f) - mu * mu;
    float rs  = rsqrtf(var + 1e-5f);
    f32x2 gv = *(const f32x2*)(gamma + lane * 2);
    f32x2 be = *(const f32x2*)(betap + lane * 2);
    float o0 = fmaxf((x0 - mu) * rs * gv.x + be.x, 0.f);
    float o1 = fmaxf((x1 - mu) * rs * gv.y + be.y, 0.f);
    if constexpr (OUTF32) {
        f32x2 o = {o0, o1};
        *(f32x2*)(outF + off) = o;
    } else {
        bf16* p = outB + off;
        p[0] = (bf16)o0; p[1] = (bf16)o1;
    }
}

// ---------------------------------------------------------------------------
extern "C" void kernel_launch(void* const* d_in, const int* in_sizes, int n_in,
                              void* d_out, int out_size, void* d_ws, size_t ws_size,
                              hipStream_t stream) {
    const float* x   = (const float*)d_in[0];
    const float* adj = (const float*)d_in[1];
    const float* W[3]  = {(const float*)d_in[2],  (const float*)d_in[6],  (const float*)d_in[10]};
    const float* bb[3] = {(const float*)d_in[3],  (const float*)d_in[7],  (const float*)d_in[11]};
    const float* gg[3] = {(const float*)d_in[4],  (const float*)d_in[8],  (const float*)d_in[12]};
    const float* be[3] = {(const float*)d_in[5],  (const float*)d_in[9],  (const float*)d_in[13]};

    char* ws = (char*)d_ws;
    size_t off = 0;
    auto alloc = [&](size_t bytes) { char* p = ws + off; off = (off + bytes + 255) & ~(size_t)255; return p; };
    bf16*  WT   = (bf16*) alloc((size_t)3 * 128 * 128 * 2);
    bf16*  tmpT = (bf16*) alloc((size_t)NB * HID * NN * 2);      // 8 MiB
    bf16*  hB   = (bf16*) alloc((size_t)NB * NN * HID * 2);      // 8 MiB
    bf16*  adjB = (bf16*) alloc((size_t)NB * NN * NN * 2);       // 128 MiB
    float* part = (float*)alloc((size_t)2 * NB * NN * HID * 4);  // 32 MiB

    float* outF = (float*)d_out;

    prep_wt<<<3, 256, 0, stream>>>(W[0], W[1], W[2], WT);

    dim3 bg(16, 2, 16);
    // ---- layer 0 (fp32 adj read fused with bf16 conversion/side-write) ----
    small_gemm<float><<<256, 256, 0, stream>>>(x, WT, tmpT);
    big_gemm<1><<<bg, 256, 0, stream>>>(adj, adjB, tmpT, part);
    reduce_ln<false><<<8192, 256, 0, stream>>>(part, bb[0], gg[0], be[0], hB, nullptr);
    // ---- layer 1 ----
    small_gemm<bf16><<<256, 256, 0, stream>>>(hB, WT + 128 * 128, tmpT);
    big_gemm<2><<<bg, 256, 0, stream>>>(adj, adjB, tmpT, part);
    reduce_ln<false><<<8192, 256, 0, stream>>>(part, bb[1], gg[1], be[1], hB, nullptr);
    // ---- layer 2 ----
    small_gemm<bf16><<<256, 256, 0, stream>>>(hB, WT + 2 * 128 * 128, tmpT);
    big_gemm<2><<<bg, 256, 0, stream>>>(adj, adjB, tmpT, part);
    reduce_ln<true><<<8192, 256, 0, stream>>>(part, bb[2], gg[2], be[2], nullptr, outF);
}

// Round 4
// 556.634 us; speedup vs baseline: 1.0596x; 1.0489x over previous
//
#include <hip/hip_runtime.h>
#include <hip/hip_bf16.h>

typedef __bf16 bf16;
typedef __bf16 bf16x4 __attribute__((ext_vector_type(4)));
typedef __bf16 bf16x8 __attribute__((ext_vector_type(8)));
typedef float  f32x2  __attribute__((ext_vector_type(2)));
typedef float  f32x4  __attribute__((ext_vector_type(4)));

static constexpr int NB  = 16;
static constexpr int NN  = 2048;
static constexpr int HID = 128;

// async 16B global -> LDS. LDS dest is wave-uniform base + lane*16.
__device__ __forceinline__ void gload_lds16(const bf16* g, bf16* l) {
    __builtin_amdgcn_global_load_lds(
        (const __attribute__((address_space(1))) unsigned int*)g,
        (__attribute__((address_space(3))) unsigned int*)l, 16, 0, 0);
}

// ---------------------------------------------------------------------------
// prep: W (128x128 fp32, [k][n]) -> WT bf16 [n][k], for all 3 layers
// ---------------------------------------------------------------------------
__global__ __launch_bounds__(256) void prep_wt(const float* __restrict__ W0,
                                               const float* __restrict__ W1,
                                               const float* __restrict__ W2,
                                               bf16* __restrict__ WT) {
    int l = blockIdx.x;
    const float* W = (l == 0) ? W0 : (l == 1) ? W1 : W2;
    bf16* out = WT + l * 128 * 128;
    int tid = threadIdx.x;
#pragma unroll
    for (int i = 0; i < 64; ++i) {
        int idx = i * 256 + tid;
        int k = idx >> 7, n = idx & 127;
        out[n * 128 + k] = (bf16)W[idx];
    }
}

// ---------------------------------------------------------------------------
// prep: x (16,2048,128) fp32 -> xT (16,128,2048) bf16  (B-operand for L0 big)
// ---------------------------------------------------------------------------
__global__ __launch_bounds__(256) void prep_xt(const float* __restrict__ x,
                                               bf16* __restrict__ xT) {
    __shared__ bf16 T[128 * 136];
    const int blk = blockIdx.x;          // 256 blocks: 16 tiles x 16 batches
    const int b = blk >> 4, node0 = (blk & 15) * 128;
    const int tid = threadIdx.x;
    const float* xb = x + ((size_t)b * NN + node0) * HID;
#pragma unroll
    for (int i = 0; i < 64; ++i) {
        int idx = i * 256 + tid;
        int node = idx >> 7, hid = idx & 127;
        T[hid * 136 + node] = (bf16)xb[(size_t)node * HID + hid];
    }
    __syncthreads();
    bf16* ob = xT + (size_t)b * HID * NN + node0;
#pragma unroll
    for (int i = 0; i < 8; ++i) {
        int flat = i * 2048 + tid * 8;
        int hid = flat >> 7, node = flat & 127;
        *(bf16x8*)(ob + (size_t)hid * NN + node) = *(const bf16x8*)(T + hid * 136 + node);
    }
}

// ---------------------------------------------------------------------------
// big GEMM (pure): g[b] (2048x128) = adj[b](2048x2048) @ h[b](2048x128)
// BM=64, BN=128(full), BK=64, 32 iters. 256 thr = 4 waves, wave-tile 32x64.
// LDS: physical 16B chunk p = row*8 + (colblk ^ (row&7)) for both tiles.
// AMODE 1: A from fp32 adj (in-register cvt) + side-write adjB bf16.
// AMODE 2: A from adjB via async global_load_lds (swizzle on src addr).
// B operand hT[b][n][node] read k(node)-contiguous.
// ---------------------------------------------------------------------------
template<int AMODE>
__global__ __launch_bounds__(256, 2) void big_gemm(const float* __restrict__ Af,
                                                   bf16* __restrict__ adjB,
                                                   const bf16* __restrict__ Bt,
                                                   bf16* __restrict__ g) {
    __shared__ bf16 As[64 * 64];     // 8 KB
    __shared__ bf16 Bs[128 * 64];    // 16 KB

    const int tid  = threadIdx.x;
    const int wave = tid >> 6, lane = tid & 63;
    const int c0 = lane & 15, q = lane >> 4;
    const int m0 = blockIdx.x * 64;
    const int b  = blockIdx.z;
    const size_t abase = (size_t)b * NN * NN;
    const bf16* Btb = Bt + (size_t)b * HID * NN;
    const int wm = wave >> 1, wn = wave & 1;

    f32x4 acc[2][4] = {};

    int prow[4], pcb[4];
#pragma unroll
    for (int j = 0; j < 4; ++j) {
        int p = j * 256 + wave * 64 + lane;
        prow[j] = p >> 3;
        pcb[j]  = (p & 7) ^ (prow[j] & 7);
    }
    const int ldsbase = wave * 512;   // elems: chunk base (wave*64)*8

    for (int kk = 0; kk < 32; ++kk) {
        const int k0 = kk * 64;
        if constexpr (AMODE == 1) {
#pragma unroll
            for (int j = 0; j < 2; ++j) {
                int gi = j * 256 + tid;
                int grow = gi >> 3, gcb = gi & 7;
                const float* src = Af + abase + (size_t)(m0 + grow) * NN + k0 + gcb * 8;
                f32x4 a  = *(const f32x4*)src;
                f32x4 b2 = *(const f32x4*)(src + 4);
                bf16x8 o = {(bf16)a.x, (bf16)a.y, (bf16)a.z, (bf16)a.w,
                            (bf16)b2.x, (bf16)b2.y, (bf16)b2.z, (bf16)b2.w};
                *(bf16x8*)(As + (grow * 8 + (gcb ^ (grow & 7))) * 8) = o;
                *(bf16x8*)(adjB + abase + (size_t)(m0 + grow) * NN + k0 + gcb * 8) = o;
            }
        } else {
#pragma unroll
            for (int j = 0; j < 2; ++j)
                gload_lds16(adjB + abase + (size_t)(m0 + prow[j]) * NN + k0 + pcb[j] * 8,
                            As + j * 2048 + ldsbase);
        }
#pragma unroll
        for (int j = 0; j < 4; ++j)
            gload_lds16(Btb + (size_t)prow[j] * NN + k0 + pcb[j] * 8,
                        Bs + j * 2048 + ldsbase);
        __syncthreads();
#pragma unroll
        for (int ks = 0; ks < 2; ++ks) {
            bf16x8 af[2], bfr[4];
#pragma unroll
            for (int mt = 0; mt < 2; ++mt) {
                int row = wm * 32 + mt * 16 + c0;
                int cb  = (ks * 4 + q) ^ (row & 7);
                af[mt] = *(const bf16x8*)(As + row * 64 + cb * 8);
            }
#pragma unroll
            for (int nt = 0; nt < 4; ++nt) {
                int row = wn * 64 + nt * 16 + c0;
                int cb  = (ks * 4 + q) ^ (row & 7);
                bfr[nt] = *(const bf16x8*)(Bs + row * 64 + cb * 8);
            }
#pragma unroll
            for (int mt = 0; mt < 2; ++mt)
#pragma unroll
                for (int nt = 0; nt < 4; ++nt)
                    acc[mt][nt] = __builtin_amdgcn_mfma_f32_16x16x32_bf16(af[mt], bfr[nt], acc[mt][nt], 0, 0, 0);
        }
        __syncthreads();
    }

    bf16* gb = g + ((size_t)b * NN + m0) * HID;
#pragma unroll
    for (int mt = 0; mt < 2; ++mt)
#pragma unroll
        for (int r = 0; r < 4; ++r) {
            int m = wm * 32 + mt * 16 + q * 4 + r;
#pragma unroll
            for (int nt = 0; nt < 4; ++nt) {
                int n = wn * 64 + nt * 16 + c0;
                gb[(size_t)m * HID + n] = (bf16)acc[mt][nt][r];
            }
        }
}

// ---------------------------------------------------------------------------
// small GEMM + fused bias/LN/ReLU: h' = relu(LN(g @ W + b))
//   g: (32768,128) bf16 row-major (k-contig). WT: [n][k] bf16.
//   FINAL=false: write hT[b][n][node] (transposed, for next big's B operand)
//   FINAL=true : write fp32 row-major to d_out
// ---------------------------------------------------------------------------
template<bool FINAL>
__global__ __launch_bounds__(256) void small_ln(const bf16* __restrict__ gin,
                                                const bf16* __restrict__ WT,
                                                const float* __restrict__ bias,
                                                const float* __restrict__ gamma,
                                                const float* __restrict__ betap,
                                                bf16* __restrict__ hT,
                                                float* __restrict__ outF) {
    __shared__ bf16 smem[2 * 128 * 72];
    bf16* As = smem;
    bf16* Bs = smem + 128 * 72;

    const int tid  = threadIdx.x;
    const int wave = tid >> 6, lane = tid & 63;
    const int c0 = lane & 15, q = lane >> 4;
    const int blk = blockIdx.x;
    const int row_g0 = blk * 128;

    f32x4 acc[2][8] = {};

    for (int kk = 0; kk < 2; ++kk) {
        const int k0 = kk * 64;
#pragma unroll
        for (int i = 0; i < 4; ++i) {
            int flat = i * 2048 + tid * 8;
            int row = flat >> 6, col = flat & 63;
            bf16x8 v = *(const bf16x8*)(gin + (size_t)(row_g0 + row) * HID + k0 + col);
            *(bf16x8*)(As + row * 72 + col) = v;
        }
#pragma unroll
        for (int i = 0; i < 4; ++i) {
            int flat = i * 2048 + tid * 8;
            int row = flat >> 6, col = flat & 63;
            bf16x8 v = *(const bf16x8*)(WT + (size_t)row * 128 + k0 + col);
            *(bf16x8*)(Bs + row * 72 + col) = v;
        }
        __syncthreads();
#pragma unroll
        for (int ks = 0; ks < 2; ++ks) {
            bf16x8 af[2];
#pragma unroll
            for (int mt = 0; mt < 2; ++mt)
                af[mt] = *(const bf16x8*)(As + (wave * 32 + mt * 16 + c0) * 72 + ks * 32 + q * 8);
#pragma unroll
            for (int nt = 0; nt < 8; ++nt) {
                bf16x8 bfr = *(const bf16x8*)(Bs + (nt * 16 + c0) * 72 + ks * 32 + q * 8);
#pragma unroll
                for (int mt = 0; mt < 2; ++mt)
                    acc[mt][nt] = __builtin_amdgcn_mfma_f32_16x16x32_bf16(af[mt], bfr, acc[mt][nt], 0, 0, 0);
            }
        }
        __syncthreads();
    }

    // epilogue: bias + LN over n(128) + ReLU
    float bv[8], gv[8], bev[8];
#pragma unroll
    for (int nt = 0; nt < 8; ++nt) {
        int n = nt * 16 + c0;
        bv[nt] = bias[n]; gv[nt] = gamma[n]; bev[nt] = betap[n];
    }
    bf16* Cs = smem;   // reuse (post-barrier)
#pragma unroll
    for (int mt = 0; mt < 2; ++mt) {
#pragma unroll
        for (int r = 0; r < 4; ++r) {
            float v[8], s1 = 0.f, s2 = 0.f;
#pragma unroll
            for (int nt = 0; nt < 8; ++nt) {
                float xv = acc[mt][nt][r] + bv[nt];
                v[nt] = xv; s1 += xv; s2 += xv * xv;
            }
#pragma unroll
            for (int off = 1; off < 16; off <<= 1) {
                s1 += __shfl_xor(s1, off);
                s2 += __shfl_xor(s2, off);
            }
            float mu  = s1 * (1.f / 128.f);
            float var = s2 * (1.f / 128.f) - mu * mu;
            float rs  = rsqrtf(var + 1e-5f);
            int m = wave * 32 + mt * 16 + q * 4 + r;   // local row in [0,128)
            if constexpr (FINAL) {
                size_t rowoff = ((size_t)row_g0 + m) * HID;
#pragma unroll
                for (int nt = 0; nt < 8; ++nt) {
                    float o = fmaxf((v[nt] - mu) * rs * gv[nt] + bev[nt], 0.f);
                    outF[rowoff + nt * 16 + c0] = o;
                }
            } else {
#pragma unroll
                for (int nt = 0; nt < 8; ++nt) {
                    float o = fmaxf((v[nt] - mu) * rs * gv[nt] + bev[nt], 0.f);
                    Cs[(nt * 16 + c0) * 136 + m] = (bf16)o;
                }
            }
        }
    }
    if constexpr (!FINAL) {
        __syncthreads();
        const int b = blk >> 4, row0 = (blk & 15) * 128;
        bf16* outp = hT + (size_t)b * HID * NN;
#pragma unroll
        for (int i = 0; i < 8; ++i) {
            int flat = i * 2048 + tid * 8;
            int n = flat >> 7, mm = flat & 127;
            *(bf16x8*)(outp + (size_t)n * NN + row0 + mm) = *(const bf16x8*)(Cs + n * 136 + mm);
        }
    }
}

// ---------------------------------------------------------------------------
extern "C" void kernel_launch(void* const* d_in, const int* in_sizes, int n_in,
                              void* d_out, int out_size, void* d_ws, size_t ws_size,
                              hipStream_t stream) {
    const float* x   = (const float*)d_in[0];
    const float* adj = (const float*)d_in[1];
    const float* W[3]  = {(const float*)d_in[2],  (const float*)d_in[6],  (const float*)d_in[10]};
    const float* bb[3] = {(const float*)d_in[3],  (const float*)d_in[7],  (const float*)d_in[11]};
    const float* gg[3] = {(const float*)d_in[4],  (const float*)d_in[8],  (const float*)d_in[12]};
    const float* be[3] = {(const float*)d_in[5],  (const float*)d_in[9],  (const float*)d_in[13]};

    char* ws = (char*)d_ws;
    size_t off = 0;
    auto alloc = [&](size_t bytes) { char* p = ws + off; off = (off + bytes + 255) & ~(size_t)255; return p; };
    bf16* WT   = (bf16*)alloc((size_t)3 * 128 * 128 * 2);
    bf16* xT   = (bf16*)alloc((size_t)NB * HID * NN * 2);   // 8 MiB
    bf16* hT   = (bf16*)alloc((size_t)NB * HID * NN * 2);   // 8 MiB
    bf16* gbuf = (bf16*)alloc((size_t)NB * NN * HID * 2);   // 8 MiB
    bf16* adjB = (bf16*)alloc((size_t)NB * NN * NN * 2);    // 128 MiB

    float* outF = (float*)d_out;

    prep_wt<<<3, 256, 0, stream>>>(W[0], W[1], W[2], WT);
    prep_xt<<<256, 256, 0, stream>>>(x, xT);

    dim3 bg(32, 1, 16);
    // ---- layer 0 (fp32 adj read fused with bf16 conversion/side-write) ----
    big_gemm<1><<<bg, 256, 0, stream>>>(adj, adjB, xT, gbuf);
    small_ln<false><<<256, 256, 0, stream>>>(gbuf, WT, bb[0], gg[0], be[0], hT, nullptr);
    // ---- layer 1 ----
    big_gemm<2><<<bg, 256, 0, stream>>>(adj, adjB, hT, gbuf);
    small_ln<false><<<256, 256, 0, stream>>>(gbuf, WT + 128 * 128, bb[1], gg[1], be[1], hT, nullptr);
    // ---- layer 2 ----
    big_gemm<2><<<bg, 256, 0, stream>>>(adj, adjB, hT, gbuf);
    small_ln<true><<<256, 256, 0, stream>>>(gbuf, WT + 2 * 128 * 128, bb[2], gg[2], be[2], nullptr, outF);
}